// Round 4
// baseline (71.435 us; speedup 1.0000x reference)
//
#include <hip/hip_runtime.h>

#define N_NODES 200000
#define TILE    32
#define NTILES  6250           // 200000 / 32 exactly
#define NBLK    1024           // 4 blocks/CU, all co-resident
#define TPB     256            // 4 waves; wave w owns features w*32..w*32+31
#define NREP    64

typedef __attribute__((ext_vector_type(8))) short short8;   // bf16x8 (4 VGPR)
typedef __attribute__((ext_vector_type(4))) float f32x4;
typedef __attribute__((ext_vector_type(2))) unsigned int u32x2;
typedef __attribute__((ext_vector_type(4))) unsigned int u32x4;

__device__ __forceinline__ unsigned int f2bf(float f) {
  // round-to-nearest-even fp32 -> bf16 bits
  unsigned int u = __builtin_bit_cast(unsigned int, f);
  u += 0x7FFFu + ((u >> 16) & 1u);
  return u >> 16;
}
__device__ __forceinline__ unsigned int pk2(float a, float b) {
  return f2bf(a) | (f2bf(b) << 16);
}
__device__ __forceinline__ short8 pk8(f32x4 lo, f32x4 hi) {
  u32x4 u = { pk2(lo[0], lo[1]), pk2(lo[2], lo[3]),
              pk2(hi[0], hi[1]), pk2(hi[2], hi[3]) };
  return __builtin_bit_cast(short8, u);
}
__device__ __forceinline__ f32x4 mfma16(short8 a, short8 b, f32x4 c) {
  return __builtin_amdgcn_mfma_f32_16x16x32_bf16(a, b, c, 0, 0, 0);
}
__device__ __forceinline__ void glds16(const char* g, char* l) {
  __builtin_amdgcn_global_load_lds(
      (const __attribute__((address_space(1))) void*)g,
      (__attribute__((address_space(3))) void*)l, 16, 0, 0);
}

__global__ __launch_bounds__(TPB, 4) void gcn_main(
    const float* __restrict__ x,  const float* __restrict__ W1,
    const float* __restrict__ b1, const float* __restrict__ W2,
    const float* __restrict__ b2, float* __restrict__ sums)
{
  __shared__ char xbuf[2][16384];   // [32 n][512 B] fp32, 16B-slot swizzled
  __shared__ char h1buf[8192];      // [32 n][256 B] bf16, 16B-slot swizzled

  const int tid  = threadIdx.x;
  const int lane = tid & 63;
  const int wid  = tid >> 6;        // 0..3: features wid*32 .. +31
  const int r    = lane & 15;       // MFMA col (node) / A-row selector
  const int g    = lane >> 4;       // 0..3: k-group

  // ---- W1,W2 as A-operand fragments in registers (lane: row f, k=ks*32+g*8+j)
  short8 w1f[2][4], w2f[2][4];
  #pragma unroll
  for (int ft = 0; ft < 2; ++ft) {
    const int f = wid * 32 + ft * 16 + r;
    #pragma unroll
    for (int ks = 0; ks < 4; ++ks) {
      const f32x4* p1 = (const f32x4*)(W1 + f * 128 + ks * 32 + g * 8);
      const f32x4* p2 = (const f32x4*)(W2 + f * 128 + ks * 32 + g * 8);
      w1f[ft][ks] = pk8(p1[0], p1[1]);
      w2f[ft][ks] = pk8(p2[0], p2[1]);
    }
  }
  float bias1[8], bias2[8];
  #pragma unroll
  for (int ft = 0; ft < 2; ++ft)
    #pragma unroll
    for (int qq = 0; qq < 4; ++qq) {
      bias1[ft * 4 + qq] = b1[wid * 32 + ft * 16 + g * 4 + qq];
      bias2[ft * 4 + qq] = b2[wid * 32 + ft * 16 + g * 4 + qq];
    }

  // ---- persistent contiguous tile range ----
  const int bid = (int)blockIdx.x;
  const int qt = NTILES / NBLK, rt_ = NTILES % NBLK;
  const int t0 = bid * qt + (bid < rt_ ? bid : rt_);
  const int t1 = t0 + qt + (bid < rt_ ? 1 : 0);

  // ---- staging maps: 1024 16B chunks; thread owns chunks tid + i*256 ----
  // LDS(row,u) <- global(row, u ^ (row&15))  [pre-swizzled source, rule #21]
  int srcoff[4], dstoff[4];
  #pragma unroll
  for (int i = 0; i < 4; ++i) {
    const int c = tid + i * 256;
    const int row = c >> 5, u = c & 31;
    srcoff[i] = row * 512 + ((u ^ (row & 15)) << 4);
    dstoff[i] = c * 16;
  }

#define STAGE(tile, buf)                                                       \
  {                                                                            \
    const char* bx = (const char*)x + (size_t)(tile) * 16384;                  \
    _Pragma("unroll")                                                          \
    for (int i = 0; i < 4; ++i) glds16(bx + srcoff[i], (buf) + dstoff[i]);     \
  }

  STAGE(t0, xbuf[0]);
  __syncthreads();                  // compiler drains vmcnt before s_barrier

  const f32x4 zero4 = {0.f, 0.f, 0.f, 0.f};
  f32x4 acc[2][2];
  float sum8[8] = {0.f, 0.f, 0.f, 0.f, 0.f, 0.f, 0.f, 0.f};

  int cur = 0;
  for (int t = t0; t < t1; ++t, cur ^= 1) {
    if (t + 1 < t1) STAGE(t + 1, xbuf[cur ^ 1]);   // async, spans L1 phase

    // ---- layer 1: C1^T[32f x 32n] = W1-slice * x-tile^T ----
    const char* xb = xbuf[cur];
    #pragma unroll
    for (int ft = 0; ft < 2; ++ft)
      #pragma unroll
      for (int nt = 0; nt < 2; ++nt) acc[ft][nt] = zero4;
    #pragma unroll
    for (int ks = 0; ks < 4; ++ks) {
      #pragma unroll
      for (int nt = 0; nt < 2; ++nt) {
        const int row = nt * 16 + r;
        const int b0  = ks * 128 + g * 32;
        f32x4 lo = *(const f32x4*)(xb + row * 512 + (b0 ^ (r << 4)));
        f32x4 hi = *(const f32x4*)(xb + row * 512 + ((b0 + 16) ^ (r << 4)));
        short8 bf = pk8(lo, hi);
        acc[0][nt] = mfma16(w1f[0][ks], bf, acc[0][nt]);
        acc[1][nt] = mfma16(w1f[1][ks], bf, acc[1][nt]);
      }
    }

    // ---- epilogue 1: bias+relu, pack pairs, b64 writes to h1 ----
    #pragma unroll
    for (int ft = 0; ft < 2; ++ft) {
      const int bq = wid * 64 + ft * 32 + g * 8;
      #pragma unroll
      for (int nt = 0; nt < 2; ++nt) {
        const int n = nt * 16 + r;
        float v0 = fmaxf(acc[ft][nt][0] + bias1[ft * 4 + 0], 0.f);
        float v1 = fmaxf(acc[ft][nt][1] + bias1[ft * 4 + 1], 0.f);
        float v2 = fmaxf(acc[ft][nt][2] + bias1[ft * 4 + 2], 0.f);
        float v3 = fmaxf(acc[ft][nt][3] + bias1[ft * 4 + 3], 0.f);
        u32x2 w = { pk2(v0, v1), pk2(v2, v3) };
        *(u32x2*)(h1buf + n * 256 + (bq ^ (r << 4))) = w;
      }
    }
    __syncthreads();

    // ---- layer 2: C2^T[32f x 32n] = W2-slice * h1^T, fused column-sum ----
    #pragma unroll
    for (int ft = 0; ft < 2; ++ft)
      #pragma unroll
      for (int nt = 0; nt < 2; ++nt) acc[ft][nt] = zero4;
    #pragma unroll
    for (int ks = 0; ks < 4; ++ks) {
      #pragma unroll
      for (int nt = 0; nt < 2; ++nt) {
        const int row = nt * 16 + r;
        short8 bf = *(const short8*)(h1buf + row * 256 +
                                     ((ks * 64 + g * 16) ^ (r << 4)));
        acc[0][nt] = mfma16(w2f[0][ks], bf, acc[0][nt]);
        acc[1][nt] = mfma16(w2f[1][ks], bf, acc[1][nt]);
      }
    }
    #pragma unroll
    for (int ft = 0; ft < 2; ++ft)
      #pragma unroll
      for (int nt = 0; nt < 2; ++nt)
        #pragma unroll
        for (int qq = 0; qq < 4; ++qq)
          sum8[ft * 4 + qq] += fmaxf(acc[ft][nt][qq] + bias2[ft * 4 + qq], 0.f);

    __syncthreads();   // h1 consumed; next xbuf staged (vmcnt drained here)
  }

  // ---- reduce over the 16 node-columns (r-lanes share the same features) ----
  #pragma unroll
  for (int k = 0; k < 8; ++k) {
    sum8[k] += __shfl_xor(sum8[k], 1, 64);
    sum8[k] += __shfl_xor(sum8[k], 2, 64);
    sum8[k] += __shfl_xor(sum8[k], 4, 64);
    sum8[k] += __shfl_xor(sum8[k], 8, 64);
  }
  if (r == 0) {
    const int rep = bid & (NREP - 1);
    #pragma unroll
    for (int ft = 0; ft < 2; ++ft)
      #pragma unroll
      for (int qq = 0; qq < 4; ++qq)
        unsafeAtomicAdd(&sums[rep * 128 + wid * 32 + ft * 16 + g * 4 + qq],
                        sum8[ft * 4 + qq]);
  }
#undef STAGE
}

// mean -> W3 -> classifier -> log_softmax, fp32, trivial cost
__global__ void gcn_tail(const float* __restrict__ sums,
                         const float* __restrict__ W3, const float* __restrict__ b3,
                         const float* __restrict__ Wl, const float* __restrict__ bl,
                         float* __restrict__ out)
{
  __shared__ float h3[128];
  __shared__ float lg[16];
  int t = threadIdx.x;   // 128 threads
  float m = 0.f;
  for (int rp = 0; rp < NREP; ++rp) m += sums[rp * 128 + t];
  h3[t] = m * (1.0f / (float)N_NODES);
  __syncthreads();
  float accv = 0.f;
  for (int k = 0; k < 128; ++k) accv += h3[k] * W3[t * 128 + k];
  float h3o = b3[t] + accv;
  __syncthreads();
  h3[t] = h3o;
  __syncthreads();
  if (t < 10) {
    float a = bl[t];
    for (int j = 0; j < 128; ++j) a += h3[j] * Wl[t * 128 + j];
    lg[t] = a;
  }
  __syncthreads();
  if (t == 0) {
    float mx = lg[0];
    for (int c = 1; c < 10; ++c) mx = fmaxf(mx, lg[c]);
    float s = 0.f;
    for (int c = 0; c < 10; ++c) s += expf(lg[c] - mx);
    float lse = mx + logf(s);
    for (int c = 0; c < 10; ++c) out[c] = lg[c] - lse;
  }
}

extern "C" void kernel_launch(void* const* d_in, const int* in_sizes, int n_in,
                              void* d_out, int out_size, void* d_ws, size_t ws_size,
                              hipStream_t stream) {
  const float* x  = (const float*)d_in[0];
  // d_in[1] = edge_index (int64) — unused: ChebConv K=1 has no propagation
  const float* W1 = (const float*)d_in[2];
  const float* b1 = (const float*)d_in[3];
  const float* W2 = (const float*)d_in[4];
  const float* b2 = (const float*)d_in[5];
  const float* W3 = (const float*)d_in[6];
  const float* b3 = (const float*)d_in[7];
  const float* Wl = (const float*)d_in[8];
  const float* bl = (const float*)d_in[9];
  float* sums = (float*)d_ws;            // NREP x 128 floats
  float* out  = (float*)d_out;

  (void)hipMemsetAsync(sums, 0, NREP * 128 * sizeof(float), stream);
  gcn_main<<<NBLK, TPB, 0, stream>>>(x, W1, b1, W2, b2, sums);
  gcn_tail<<<1, 128, 0, stream>>>(sums, W3, b3, Wl, bl, out);
}

// Round 5
// 63.210 us; speedup vs baseline: 1.1301x; 1.1301x over previous
//
#include <hip/hip_runtime.h>

#define N_NODES 200000
#define NTILES  6250        // 32-node tiles, exact
#define NBLK    256         // 1 block/CU (128KB LDS)
#define TPB     512         // 8 waves, each independent after W-stage
#define NWAVES  2048        // NBLK * 8
#define NREP    64
#define LDS_BYTES 131072    // 64KB W1|W2 bf16 swizzled + 8 x 8KB per-wave h1

typedef __attribute__((ext_vector_type(8))) short short8;   // bf16x8 (4 VGPR)
typedef __attribute__((ext_vector_type(4))) float f32x4;
typedef __attribute__((ext_vector_type(4))) unsigned int u32x4;

__device__ __forceinline__ unsigned int f2bf(float f) {
  // round-to-nearest-even fp32 -> bf16 bits
  unsigned int u = __builtin_bit_cast(unsigned int, f);
  u += 0x7FFFu + ((u >> 16) & 1u);
  return u >> 16;
}
__device__ __forceinline__ unsigned int pk2(float a, float b) {
  return f2bf(a) | (f2bf(b) << 16);
}
__device__ __forceinline__ short8 pk8(f32x4 lo, f32x4 hi) {
  u32x4 u = { pk2(lo[0], lo[1]), pk2(lo[2], lo[3]),
              pk2(hi[0], hi[1]), pk2(hi[2], hi[3]) };
  return __builtin_bit_cast(short8, u);
}
__device__ __forceinline__ f32x4 mfma16(short8 a, short8 b, f32x4 c) {
  return __builtin_amdgcn_mfma_f32_16x16x32_bf16(a, b, c, 0, 0, 0);
}

__global__ __launch_bounds__(TPB, 2) void gcn_main(
    const float* __restrict__ x,  const float* __restrict__ W1,
    const float* __restrict__ b1, const float* __restrict__ W2,
    const float* __restrict__ b2, float* __restrict__ sums)
{
  extern __shared__ char lds[];
  char* const wlds = lds;                      // W1 @0, W2 @32768 (bf16 swz)
  const int tid  = threadIdx.x;
  const int lane = tid & 63;
  const int wid  = tid >> 6;
  char* const h1 = lds + 65536 + wid * 8192;   // PRIVATE per-wave slab
  const int r = lane & 15;                     // MFMA row/col-in-16
  const int g = lane >> 4;                     // k-group 0..3

  const int wgid = (int)blockIdx.x * 8 + wid;

  // ---- prologue: issue x loads for first tile (head start over W-stage) ----
  int t = wgid;                                // wgid < NTILES always
  f32x4 xf[8][2];                              // fp32 in flight, static idx
  {
    const float* bx = x + (size_t)t * 4096;
    #pragma unroll
    for (int nt = 0; nt < 2; ++nt)
      #pragma unroll
      for (int ks = 0; ks < 4; ++ks) {
        const float* p = bx + (nt * 16 + r) * 128 + ks * 32 + g * 8;
        xf[nt * 4 + ks][0] = *(const f32x4*)(p);
        xf[nt * 4 + ks][1] = *(const f32x4*)(p + 4);
      }
  }

  // ---- stage W1,W2 into LDS as swizzled bf16 A-tiles ----
  #pragma unroll
  for (int l = 0; l < 2; ++l) {
    const float* W = l ? W2 : W1;
    char* dst = wlds + l * 32768;
    #pragma unroll
    for (int i = 0; i < 4; ++i) {
      const int c = tid + i * 512;             // 16B-chunk id 0..2047
      const int f = c >> 4, s = c & 15;
      const f32x4* src = (const f32x4*)(W + f * 128 + s * 8);
      *(short8*)(dst + f * 256 + ((s ^ (f & 7)) << 4)) = pk8(src[0], src[1]);
    }
  }
  __syncthreads();   // the ONLY barrier; loop below is barrier-free

  const f32x4 zero4 = {0.f, 0.f, 0.f, 0.f};
  f32x4 sum8[8];
  #pragma unroll
  for (int ft = 0; ft < 8; ++ft) sum8[ft] = zero4;

  while (t < NTILES) {
    // pack current tile's B-frags -> frees xf for next-tile prefetch
    short8 xb[8];
    #pragma unroll
    for (int q = 0; q < 8; ++q) xb[q] = pk8(xf[q][0], xf[q][1]);

    const int tn = t + NWAVES;
    if (tn < NTILES) {                         // wave-uniform branch
      const float* bx = x + (size_t)tn * 4096;
      #pragma unroll
      for (int nt = 0; nt < 2; ++nt)
        #pragma unroll
        for (int ks = 0; ks < 4; ++ks) {
          const float* p = bx + (nt * 16 + r) * 128 + ks * 32 + g * 8;
          xf[nt * 4 + ks][0] = *(const f32x4*)(p);
          xf[nt * 4 + ks][1] = *(const f32x4*)(p + 4);
        }
    }

    // ---- layer 1: A = W1 (LDS), B = x frags; acc q -> h1[f][n] ----
    f32x4 acc[8][2];
    #pragma unroll
    for (int ft = 0; ft < 8; ++ft) { acc[ft][0] = zero4; acc[ft][1] = zero4; }
    #pragma unroll
    for (int ks = 0; ks < 4; ++ks) {
      #pragma unroll
      for (int ft = 0; ft < 8; ++ft) {
        short8 af = *(const short8*)(wlds + (ft * 16 + r) * 256 +
                                     (((ks * 4 + g) ^ (r & 7)) << 4));
        acc[ft][0] = mfma16(af, xb[0 * 4 + ks], acc[ft][0]);
        acc[ft][1] = mfma16(af, xb[1 * 4 + ks], acc[ft][1]);
      }
    }

    // ---- epilogue 1: bias+relu, pack 4 features, b64 to private slab ----
    #pragma unroll
    for (int ft = 0; ft < 8; ++ft) {
      const f32x4 bf = *(const f32x4*)(b1 + ft * 16 + g * 4);   // L1-hot
      const int s = ft * 2 + (g >> 1);
      const int half = (g & 1) * 8;
      #pragma unroll
      for (int nt = 0; nt < 2; ++nt) {
        const int n = nt * 16 + r;
        float v0 = fmaxf(acc[ft][nt][0] + bf[0], 0.f);
        float v1 = fmaxf(acc[ft][nt][1] + bf[1], 0.f);
        float v2 = fmaxf(acc[ft][nt][2] + bf[2], 0.f);
        float v3 = fmaxf(acc[ft][nt][3] + bf[3], 0.f);
        unsigned long long w =
            (unsigned long long)pk2(v0, v1) |
            ((unsigned long long)pk2(v2, v3) << 32);
        *(unsigned long long*)(h1 + n * 256 + ((s ^ (n & 7)) << 4) + half) = w;
      }
    }

    // ---- layer 2: A = W2 (LDS), B = h1 slab (same-wave, lgkm only) ----
    #pragma unroll
    for (int ft = 0; ft < 8; ++ft) { acc[ft][0] = zero4; acc[ft][1] = zero4; }
    #pragma unroll
    for (int ks = 0; ks < 4; ++ks) {
      const int n1 = 16 + r;
      short8 hb0 = *(const short8*)(h1 + r  * 256 +
                                    (((ks * 4 + g) ^ (r  & 7)) << 4));
      short8 hb1 = *(const short8*)(h1 + n1 * 256 +
                                    (((ks * 4 + g) ^ (n1 & 7)) << 4));
      #pragma unroll
      for (int ft = 0; ft < 8; ++ft) {
        short8 af = *(const short8*)(wlds + 32768 + (ft * 16 + r) * 256 +
                                     (((ks * 4 + g) ^ (r & 7)) << 4));
        acc[ft][0] = mfma16(af, hb0, acc[ft][0]);
        acc[ft][1] = mfma16(af, hb1, acc[ft][1]);
      }
    }

    // ---- epilogue 2: bias+relu, accumulate column sums in registers ----
    #pragma unroll
    for (int ft = 0; ft < 8; ++ft) {
      const f32x4 bf = *(const f32x4*)(b2 + ft * 16 + g * 4);
      #pragma unroll
      for (int nt = 0; nt < 2; ++nt)
        #pragma unroll
        for (int q = 0; q < 4; ++q)
          sum8[ft][q] += fmaxf(acc[ft][nt][q] + bf[q], 0.f);
    }

    t = tn;
  }

  // ---- reduce over 16 node-lanes; g-lanes hold disjoint features ----
  #pragma unroll
  for (int ft = 0; ft < 8; ++ft)
    #pragma unroll
    for (int q = 0; q < 4; ++q) {
      float v = sum8[ft][q];
      v += __shfl_xor(v, 1, 64);
      v += __shfl_xor(v, 2, 64);
      v += __shfl_xor(v, 4, 64);
      v += __shfl_xor(v, 8, 64);
      sum8[ft][q] = v;
    }
  if (r == 0) {
    const int rep = wgid & (NREP - 1);
    #pragma unroll
    for (int ft = 0; ft < 8; ++ft)
      #pragma unroll
      for (int q = 0; q < 4; ++q)
        unsafeAtomicAdd(&sums[rep * 128 + ft * 16 + g * 4 + q], sum8[ft][q]);
  }
}

// mean -> W3 -> classifier -> log_softmax, fp32, trivial cost
__global__ void gcn_tail(const float* __restrict__ sums,
                         const float* __restrict__ W3, const float* __restrict__ b3,
                         const float* __restrict__ Wl, const float* __restrict__ bl,
                         float* __restrict__ out)
{
  __shared__ float h3[128];
  __shared__ float lg[16];
  int t = threadIdx.x;   // 128 threads
  float m = 0.f;
  for (int rp = 0; rp < NREP; ++rp) m += sums[rp * 128 + t];
  h3[t] = m * (1.0f / (float)N_NODES);
  __syncthreads();
  float accv = 0.f;
  for (int k = 0; k < 128; ++k) accv += h3[k] * W3[t * 128 + k];
  float h3o = b3[t] + accv;
  __syncthreads();
  h3[t] = h3o;
  __syncthreads();
  if (t < 10) {
    float a = bl[t];
    for (int j = 0; j < 128; ++j) a += h3[j] * Wl[t * 128 + j];
    lg[t] = a;
  }
  __syncthreads();
  if (t == 0) {
    float mx = lg[0];
    for (int c = 1; c < 10; ++c) mx = fmaxf(mx, lg[c]);
    float s = 0.f;
    for (int c = 0; c < 10; ++c) s += expf(lg[c] - mx);
    float lse = mx + logf(s);
    for (int c = 0; c < 10; ++c) out[c] = lg[c] - lse;
  }
}

extern "C" void kernel_launch(void* const* d_in, const int* in_sizes, int n_in,
                              void* d_out, int out_size, void* d_ws, size_t ws_size,
                              hipStream_t stream) {
  const float* x  = (const float*)d_in[0];
  // d_in[1] = edge_index (int64) — unused: ChebConv K=1 has no propagation
  const float* W1 = (const float*)d_in[2];
  const float* b1 = (const float*)d_in[3];
  const float* W2 = (const float*)d_in[4];
  const float* b2 = (const float*)d_in[5];
  const float* W3 = (const float*)d_in[6];
  const float* b3 = (const float*)d_in[7];
  const float* Wl = (const float*)d_in[8];
  const float* bl = (const float*)d_in[9];
  float* sums = (float*)d_ws;            // NREP x 128 floats
  float* out  = (float*)d_out;

  (void)hipFuncSetAttribute((const void*)gcn_main,
                            hipFuncAttributeMaxDynamicSharedMemorySize,
                            LDS_BYTES);
  (void)hipMemsetAsync(sums, 0, NREP * 128 * sizeof(float), stream);
  gcn_main<<<NBLK, TPB, LDS_BYTES, stream>>>(x, W1, b1, W2, b2, sums);
  gcn_tail<<<1, 128, 0, stream>>>(sums, W3, b3, Wl, bl, out);
}